// Round 12
// baseline (4558.234 us; speedup 1.0000x reference)
//
#include <hip/hip_runtime.h>

typedef __attribute__((ext_vector_type(4)))  int   int32x4;
typedef __attribute__((ext_vector_type(16))) int   int32x16;
typedef __attribute__((ext_vector_type(16))) float f32x16;
typedef unsigned char uchar;

#define HID 512
#define BT 32
#define OUTN 12

// H/O global scale: |H| ~ N(0, 1/sqrt(512)) => sigma 0.0442, 6.36-sigma = 0.281
#define SH 0.28125f
#define S_COMB (SH / 16129.0f)          // SH / 127^2

// ---- quantize into 2 signed-int8 levels: f ~= SH/127 * (q1 + q2/128)
static __device__ __forceinline__ void quant2(float f, int& q1, int& q2) {
    float h  = fminf(fmaxf(f * (1.0f / SH), -1.0f), 1.0f) * 127.0f;
    float Q1 = rintf(h);
    float r1 = (h - Q1) * 128.0f;
    float Q2 = rintf(r1);
    q1 = (int)Q1; q2 = (int)Q2;
}

// ---- pack H (fp32 [512][512]) into 2 i8 level-streams, A-frag order (A row = n):
//   chunk addr = slice*32768 + ks*2048 + L*1024 + l*16, slice = n>>5
__global__ void pack_h(const float* __restrict__ Hw, uchar* __restrict__ Hpk) {
    int t  = blockIdx.x * blockDim.x + threadIdx.x;   // 0..32767
    int l  = t & 63;
    int L  = (t >> 6) & 1;
    int ks = (t >> 7) & 15;
    int w  = t >> 11;                                 // slice 0..15
    int n  = w * 32 + (l & 31);
    int k0 = ks * 32 + (l >> 5) * 16;
    uint d[4] = {0, 0, 0, 0};
#pragma unroll
    for (int j = 0; j < 16; ++j) {
        int q1, q2;
        quant2(Hw[n * HID + k0 + j], q1, q2);
        int q = L ? q2 : q1;
        d[j >> 2] |= ((uint)(q & 255)) << (8 * (j & 3));
    }
    *(uint4*)(Hpk + (size_t)t * 16) = make_uint4(d[0], d[1], d[2], d[3]);
}

// ---- pack O (fp32 [12][512]) into 2 i8 level-streams (rows padded to 16), for 16x16x64:
//   Opk[ (L*8 + ks)*1024 + l*16 + j ] = qL( O[o = l&15][k = ks*64 + (l>>4)*16 + j] )
__global__ void pack_o(const float* __restrict__ Ow, uchar* __restrict__ Opk) {
    int t  = blockIdx.x * blockDim.x + threadIdx.x;   // 0..1023
    int l  = t & 63;
    int ks = (t >> 6) & 7;
    int L  = t >> 9;                                  // 0..1
    int o  = l & 15;
    int k0 = ks * 64 + (l >> 4) * 16;
    uint d[4] = {0, 0, 0, 0};
#pragma unroll
    for (int j = 0; j < 16; ++j) {
        float f = (o < OUTN) ? Ow[o * HID + k0 + j] : 0.0f;
        int q1, q2;
        quant2(f, q1, q2);
        int q = L ? q2 : q1;
        d[j >> 2] |= ((uint)(q & 255)) << (8 * (j & 3));
    }
    *(uint4*)(Opk + (size_t)t * 16) = make_uint4(d[0], d[1], d[2], d[3]);
}

// LDS map (144 KB total):
//   [0, 32768)        z: 2 planes [32 m][512 n] i8, XOR-swizzled, SINGLE buffered
//   [32768, 98304)    static h2 (ks 12..15): (w*8 + tau*4 + i)*1024 + l*16
//   [98304, 114688)   Opk copy (16 KB, verbatim)
//   [114688, 147456)  DMA ring: w*4096 + slot*1024

// ---- output GEMM (2 rotating waves), op from LDS, z single buffer
static __device__ __forceinline__ void out_gemm(const char* zsc, const char* opb,
                                                const float* mbv, int wloc, int l,
                                                float* __restrict__ out,
                                                int b0, int trow, int T) {
    int32x4 aA = {0, 0, 0, 0}, aB = {0, 0, 0, 0};
    const int m     = l & 15;
    const int om    = wloc * 16 + m;
    const int obase = om * 512;
    const int oxor  = (om & 15) << 4;
    const int okb   = (l >> 4) * 16;
#pragma unroll
    for (int ks = 0; ks < 8; ++ks) {
        int32x4 o1 = *(const int32x4*)(opb + ks * 1024 + (size_t)l * 16);
        int32x4 o2 = *(const int32x4*)(opb + 8192 + ks * 1024 + (size_t)l * 16);
        int off = obase + ((ks * 64 + okb) ^ oxor);
        int32x4 z1 = *(const int32x4*)(zsc + off);
        int32x4 z2 = *(const int32x4*)(zsc + 16384 + off);
        aA = __builtin_amdgcn_mfma_i32_16x16x64_i8(o1, z1, aA, 0, 0, 0);
        aB = __builtin_amdgcn_mfma_i32_16x16x64_i8(o1, z2, aB, 0, 0, 0);
        aB = __builtin_amdgcn_mfma_i32_16x16x64_i8(o2, z1, aB, 0, 0, 0);
    }
    if ((l >> 4) < 3) {
        float4 y4;
        float* yp = &y4.x;
#pragma unroll
        for (int r = 0; r < 4; ++r) {
            float logit = mbv[r] + S_COMB * ((float)aA[r] + 0.0078125f * (float)aB[r]);
            yp[r] = __fdividef(1.0f, 1.0f + __expf(-logit));
        }
        *(float4*)(out + ((size_t)(b0 + om) * T + trow) * OUTN + (l >> 4) * 4) = y4;
    }
}

// issue chunk ((S)+4)%28 into ring slot (S)&3. chunks: c<24 -> h2 ks=c>>1, tau=c&1;
// c>=24 -> h1 ks=14+((c-24)>>1), tau=c&1.
#define ISSUE_SITE(S)                                                                   \
    {                                                                                   \
        const int c_   = ((S) + 4) % 28;                                                \
        const int tt_  = c_ & 1;                                                        \
        const int kk_  = (c_ < 24) ? (c_ >> 1) : (14 + ((c_ - 24) >> 1));               \
        const int lvl_ = (c_ < 24) ? 1024 : 0;                                          \
        const uchar* g_ = Hpk + (size_t)(2 * w + tt_) * 32768 + kk_ * 2048 + lvl_       \
                          + (size_t)l * 16;                                             \
        __builtin_amdgcn_global_load_lds(                                               \
            (const __attribute__((address_space(1))) uint*)g_,                          \
            (__attribute__((address_space(3))) uint*)(ringb + ((S) & 3) * 1024),        \
            16, 0, 0);                                                                  \
    }

#define WAITV2()                                                \
    asm volatile("s_waitcnt vmcnt(2)" ::: "memory");            \
    __builtin_amdgcn_sched_barrier(0)

#define BARRIER()                                               \
    asm volatile("s_waitcnt lgkmcnt(0)" ::: "memory");          \
    __builtin_amdgcn_s_barrier();                               \
    asm volatile("" ::: "memory");                              \
    __builtin_amdgcn_sched_barrier(0)

#define PHASE2(A2, A3, TAU)                                                             \
    {                                                                                   \
        const int h5 = l >> 5;                                                          \
        _Pragma("unroll")                                                               \
        for (int rq = 0; rq < 4; ++rq) {                                                \
            uint d1 = 0, d2 = 0;                                                        \
            _Pragma("unroll")                                                           \
            for (int e = 0; e < 4; ++e) {                                               \
                int r = rq * 4 + e;                                                     \
                float s = (float)(A2)[r] + 0.0078125f * (float)(A3)[r];                 \
                float u = fmaf(S_COMB, s, (TAU) ? drv1[r] : drv0[r]);                   \
                float ex = __expf(2.0f * u);                                            \
                float z  = 1.0f - __fdividef(2.0f, ex + 1.0f);                          \
                float h  = z * 127.0f;                                                  \
                float Q1 = rintf(h);                                                    \
                float r1 = (h - Q1) * 128.0f;                                           \
                float Q2 = rintf(r1);                                                   \
                d1 |= ((uint)((int)Q1 & 255)) << (8 * e);                               \
                d2 |= ((uint)((int)Q2 & 255)) << (8 * e);                               \
            }                                                                           \
            int nb  = w * 64 + (TAU) * 32 + 8 * rq + 4 * h5;                            \
            int off = abase + (nb ^ axor);                                              \
            *(uint*)(zsc + off)         = d1;                                           \
            *(uint*)(zsc + 16384 + off) = d2;                                           \
        }                                                                               \
    }

__launch_bounds__(512)
__global__ void ctrnn_kernel(const float* __restrict__ x,
                             const int*   __restrict__ Tp,
                             const float* __restrict__ Iw,
                             const float* __restrict__ v,
                             const float* __restrict__ mb,
                             const uchar* __restrict__ Hpk,
                             const uchar* __restrict__ Opk,
                             float* __restrict__ out) {
    __shared__ uint4 zs4[9216];   // 144 KB
    char* zsc = (char*)zs4;

    const int T   = Tp[0];
    const int tid = threadIdx.x;
    const int l   = tid & 63;
    const int w   = tid >> 6;                 // wave 0..7; owns n in [w*64, w*64+64)
    const int b0  = blockIdx.x * BT;

    char* ringb = zsc + 114688 + w * 4096;
    const char* opb = zsc + 98304;

    // zero z (32 KB = 2048 uint4)
#pragma unroll
    for (int i = 0; i < 4; ++i) zs4[tid + i * 512] = make_uint4(0, 0, 0, 0);

    // stage static h2 (ks 12..15, both tiles): 64 KB
#pragma unroll
    for (int tau = 0; tau < 2; ++tau)
#pragma unroll
        for (int i = 0; i < 4; ++i) {
            const uchar* src = Hpk + (size_t)(2 * w + tau) * 32768 + (12 + i) * 2048
                               + 1024 + (size_t)l * 16;
            *(uint4*)(zsc + 32768 + (size_t)(w * 8 + tau * 4 + i) * 1024 + (size_t)l * 16)
                = *(const uint4*)src;
        }

    // stage Opk (16 KB verbatim)
#pragma unroll
    for (int i = 0; i < 2; ++i)
        ((uint4*)(zsc + 98304))[tid + i * 512] = ((const uint4*)Opk)[tid + i * 512];

    // h1 register cache for ks 0..13, both tiles (112 VGPRs)
    int32x4 h1R0[14], h1R1[14];
#pragma unroll
    for (int ks = 0; ks < 14; ++ks) {
        h1R0[ks] = *(const int32x4*)(Hpk + (size_t)(2 * w + 0) * 32768 + ks * 2048 + (size_t)l * 16);
        h1R1[ks] = *(const int32x4*)(Hpk + (size_t)(2 * w + 1) * 32768 + ks * 2048 + (size_t)l * 16);
    }

    // drive (fp32, exact): lane owns m = l&31; tile tau -> n = w*64 + tau*32 + nset(r)
    const float xm = x[b0 + (l & 31)];
    f32x16 drv0, drv1;
#pragma unroll
    for (int r = 0; r < 16; ++r) {
        int ns = (r & 3) + 8 * (r >> 2) + 4 * (l >> 5);
        int n0 = w * 64 + ns, n1 = w * 64 + 32 + ns;
        drv0[r] = fmaf(xm, Iw[n0], v[n0]);
        drv1[r] = fmaf(xm, Iw[n1], v[n1]);
    }

    float mbv[4] = {0.f, 0.f, 0.f, 0.f};
    if ((l >> 4) < 3) {
#pragma unroll
        for (int r = 0; r < 4; ++r) mbv[r] = mb[(l >> 4) * 4 + r];
    }

    // z B-frag addressing
    const int am    = l & 31;
    const int abase = am * 512;
    const int axor  = (am & 15) << 4;
    const int akb   = (l >> 5) * 16;

    __syncthreads();

    // ring prologue: chunks 0..3 into slots 0..3 (ISSUE_SITE(24..27) issues chunk (S+4)%28)
    ISSUE_SITE(24); ISSUE_SITE(25); ISSUE_SITE(26); ISSUE_SITE(27);

#pragma unroll 1
    for (int t = 0; t < T; ++t) {
        // ---- phase 3 (rotating wave pair): y_{t-1} from z_t
        if (((w >> 1) == (t & 3)) && t > 0)
            out_gemm(zsc, opb, mbv, w & 1, l, out, b0, t - 1, T);

        // ---- phase 1: 6 MFMAs per ks (2 tiles x 3 terms), h1 from regs/ring,
        //      h2 from ring/static, z from LDS (shared across tiles)
        int32x16 a2t0 = {0}, a3t0 = {0}, a2t1 = {0}, a3t1 = {0};
#pragma unroll
        for (int ks = 0; ks < 16; ++ks) {
            int off = abase + ((ks * 32 + akb) ^ axor);
            int32x4 z1 = *(const int32x4*)(zsc + off);
            int32x4 z2 = *(const int32x4*)(zsc + 16384 + off);

            int32x4 h2a, h2b, h1a, h1b;
            if (ks <= 11) {                 // h2 from ring (sites 2ks, 2ks+1)
                WAITV2();
                h2a = *(const int32x4*)(ringb + ((2 * ks) & 3) * 1024 + (size_t)l * 16);
                h2b = *(const int32x4*)(ringb + ((2 * ks + 1) & 3) * 1024 + (size_t)l * 16);
            } else {                        // h2 static (i = ks-12)
                int i = ks - 12;
                h2a = *(const int32x4*)(zsc + 32768 + (size_t)(w * 8 + i) * 1024 + (size_t)l * 16);
                h2b = *(const int32x4*)(zsc + 32768 + (size_t)(w * 8 + 4 + i) * 1024 + (size_t)l * 16);
            }
            if (ks >= 14) {                 // h1 from ring (sites 24+2(ks-14), +1)
                WAITV2();
                int s0 = 24 + (ks - 14) * 2;
                h1a = *(const int32x4*)(ringb + (s0 & 3) * 1024 + (size_t)l * 16);
                h1b = *(const int32x4*)(ringb + ((s0 + 1) & 3) * 1024 + (size_t)l * 16);
            } else {
                h1a = h1R0[ks];
                h1b = h1R1[ks];
            }

            a2t0 = __builtin_amdgcn_mfma_i32_32x32x32_i8(h1a, z1, a2t0, 0, 0, 0);
            a3t0 = __builtin_amdgcn_mfma_i32_32x32x32_i8(h1a, z2, a3t0, 0, 0, 0);
            a3t0 = __builtin_amdgcn_mfma_i32_32x32x32_i8(h2a, z1, a3t0, 0, 0, 0);
            a2t1 = __builtin_amdgcn_mfma_i32_32x32x32_i8(h1b, z1, a2t1, 0, 0, 0);
            a3t1 = __builtin_amdgcn_mfma_i32_32x32x32_i8(h1b, z2, a3t1, 0, 0, 0);
            a3t1 = __builtin_amdgcn_mfma_i32_32x32x32_i8(h2b, z1, a3t1, 0, 0, 0);

            if (ks <= 11) {                 // refill the 2 slots just consumed
                __builtin_amdgcn_sched_barrier(0);
                ISSUE_SITE(2 * ks); ISSUE_SITE(2 * ks + 1);
            }
            if (ks >= 14) {
                __builtin_amdgcn_sched_barrier(0);
                int s0 = 24 + (ks - 14) * 2;
                ISSUE_SITE(s0); ISSUE_SITE(s0 + 1);
            }
        }

        BARRIER();   // all reads of z_t complete (ring DMA stays in flight)

        // ---- phase 2: z_{t+1} = quant2(tanh(u)) written in place
        PHASE2(a2t0, a3t0, 0);
        PHASE2(a2t1, a3t1, 1);

        BARRIER();   // z_{t+1} visible
    }

    // ---- epilogue: y_{T-1} from z_T (waves 0,1)
    if (w < 2)
        out_gemm(zsc, opb, mbv, w, l, out, b0, T - 1, T);
}

extern "C" void kernel_launch(void* const* d_in, const int* in_sizes, int n_in,
                              void* d_out, int out_size, void* d_ws, size_t ws_size,
                              hipStream_t stream) {
    const float* x  = (const float*)d_in[0];
    const int*   T  = (const int*)d_in[1];
    const float* Iw = (const float*)d_in[2];
    const float* Hw = (const float*)d_in[3];
    const float* Ow = (const float*)d_in[4];
    const float* v  = (const float*)d_in[5];
    const float* m  = (const float*)d_in[6];
    float* out = (float*)d_out;

    uchar* Hpk = (uchar*)d_ws;                   // 16*16*2*1024 = 524288 B
    uchar* Opk = Hpk + 524288;                   // 16384 B

    pack_h<<<dim3(128), dim3(256), 0, stream>>>(Hw, Hpk);
    pack_o<<<dim3(4),   dim3(256), 0, stream>>>(Ow, Opk);
    ctrnn_kernel<<<dim3(256), dim3(512), 0, stream>>>(x, T, Iw, v, m, Hpk, Opk, out);
}

// Round 13
// 2246.802 us; speedup vs baseline: 2.0288x; 2.0288x over previous
//
#include <hip/hip_runtime.h>

typedef __attribute__((ext_vector_type(4)))  int   int32x4;
typedef __attribute__((ext_vector_type(16))) int   int32x16;
typedef __attribute__((ext_vector_type(16))) float f32x16;
typedef unsigned char uchar;

#define HID 512
#define BT 32
#define OUTN 12

// H/O global scale: |H| ~ N(0, 1/sqrt(512)) => sigma 0.0442, 6.36-sigma = 0.281
#define SH 0.28125f
#define S_COMB (SH / 16129.0f)          // SH / 127^2

// ---- quantize into 2 signed-int8 levels: f ~= SH/127 * (q1 + q2/128)
static __device__ __forceinline__ void quant2(float f, int& q1, int& q2) {
    float h  = fminf(fmaxf(f * (1.0f / SH), -1.0f), 1.0f) * 127.0f;
    float Q1 = rintf(h);
    float r1 = (h - Q1) * 128.0f;
    float Q2 = rintf(r1);
    q1 = (int)Q1; q2 = (int)Q2;
}

// ---- pack H (fp32 [512][512]) into 2 i8 level-streams, A-frag order (A row = n):
//   Hpk[ ((w*16 + ks)*2 + L)*1024 + l*16 + j ] =
//     qL( H[n = w*32 + (l&31)][k = ks*32 + (l>>5)*16 + j] )
__global__ void pack_h(const float* __restrict__ Hw, uchar* __restrict__ Hpk) {
    int t  = blockIdx.x * blockDim.x + threadIdx.x;   // 0..32767
    int l  = t & 63;
    int L  = (t >> 6) & 1;
    int ks = (t >> 7) & 15;
    int w  = t >> 11;                                 // 0..15
    int n  = w * 32 + (l & 31);
    int k0 = ks * 32 + (l >> 5) * 16;
    uint d[4] = {0, 0, 0, 0};
#pragma unroll
    for (int j = 0; j < 16; ++j) {
        int q1, q2;
        quant2(Hw[n * HID + k0 + j], q1, q2);
        int q = L ? q2 : q1;
        d[j >> 2] |= ((uint)(q & 255)) << (8 * (j & 3));
    }
    *(uint4*)(Hpk + (size_t)t * 16) = make_uint4(d[0], d[1], d[2], d[3]);
}

// ---- pack O (fp32 [12][512]) into 2 i8 level-streams (rows padded to 16), for 16x16x64:
//   Opk[ (L*8 + ks)*1024 + l*16 + j ] = qL( O[o = l&15][k = ks*64 + (l>>4)*16 + j] )
__global__ void pack_o(const float* __restrict__ Ow, uchar* __restrict__ Opk) {
    int t  = blockIdx.x * blockDim.x + threadIdx.x;   // 0..1023
    int l  = t & 63;
    int ks = (t >> 6) & 7;
    int L  = t >> 9;                                  // 0..1
    int o  = l & 15;
    int k0 = ks * 64 + (l >> 4) * 16;
    uint d[4] = {0, 0, 0, 0};
#pragma unroll
    for (int j = 0; j < 16; ++j) {
        float f = (o < OUTN) ? Ow[o * HID + k0 + j] : 0.0f;
        int q1, q2;
        quant2(f, q1, q2);
        int q = L ? q2 : q1;
        d[j >> 2] |= ((uint)(q & 255)) << (8 * (j & 3));
    }
    *(uint4*)(Opk + (size_t)t * 16) = make_uint4(d[0], d[1], d[2], d[3]);
}

// z LDS: per buffer 2 level-planes of [32 m][512 n] int8 (16KB each), XOR-swizzled:
//   byte(m, k, L) = L*16384 + m*512 + (k ^ ((m&15)<<4)); buffer stride 32768
// h2-stage LDS (ks 10..15 of each wave's residual plane) at byte 65536:
//   [w][ks-10][l][16B] -> 65536 + ((w*6 + i)*64 + l)*16   (96 KB; total 160 KB)

// ---- output GEMM (2 rotating waves): y = sigmoid(z @ O^T + m), swapped operands:
// D[i=o][j=m]: col = l&15 = m (wave-local batch), row o = (l>>4)*4 + r
static __device__ __forceinline__ void out_gemm(const char* zr, const uchar* __restrict__ Opk,
                                                const float* mbv, int wloc, int l,
                                                float* __restrict__ out,
                                                int b0, int trow, int T) {
    int32x4 aA = {0, 0, 0, 0}, aB = {0, 0, 0, 0};
    const int m     = l & 15;
    const int om    = wloc * 16 + m;       // block-local batch row in z planes
    const int obase = om * 512;
    const int oxor  = (om & 15) << 4;      // == m<<4
    const int okb   = (l >> 4) * 16;
    const uchar* op = Opk + (size_t)l * 16;
#pragma unroll
    for (int ks = 0; ks < 8; ++ks) {
        int32x4 o1 = *(const int32x4*)(op + ks * 1024);
        int32x4 o2 = *(const int32x4*)(op + 8192 + ks * 1024);
        int off = obase + ((ks * 64 + okb) ^ oxor);
        int32x4 z1 = *(const int32x4*)(zr + off);
        int32x4 z2 = *(const int32x4*)(zr + 16384 + off);
        aA = __builtin_amdgcn_mfma_i32_16x16x64_i8(o1, z1, aA, 0, 0, 0);
        aB = __builtin_amdgcn_mfma_i32_16x16x64_i8(o1, z2, aB, 0, 0, 0);
        aB = __builtin_amdgcn_mfma_i32_16x16x64_i8(o2, z1, aB, 0, 0, 0);
    }
    if ((l >> 4) < 3) {
        float4 y4;
        float* yp = &y4.x;
#pragma unroll
        for (int r = 0; r < 4; ++r) {
            float logit = mbv[r] + S_COMB * ((float)aA[r] + 0.0078125f * (float)aB[r]);
            yp[r] = __fdividef(1.0f, 1.0f + __expf(-logit));
        }
        *(float4*)(out + ((size_t)(b0 + om) * T + trow) * OUTN + (l >> 4) * 4) = y4;
    }
}

// phase-1 loop sections (integer accumulation commutes -> order is free per wave)
#define KS_GLOBAL_LOOP                                                                  \
    _Pragma("unroll 2")                                                                 \
    for (int ks = 0; ks < 10; ++ks) {                                                   \
        const uchar* hk = hp + (size_t)ks * 2048;                                       \
        int32x4 h1 = *(const int32x4*)(hk);                                             \
        int32x4 h2 = *(const int32x4*)(hk + 1024);                                      \
        int off = abase + ((ks * 32 + akb) ^ axor);                                     \
        int32x4 z1 = *(const int32x4*)(zr + off);                                       \
        int32x4 z2 = *(const int32x4*)(zr + 16384 + off);                               \
        a2 = __builtin_amdgcn_mfma_i32_32x32x32_i8(h1, z1, a2, 0, 0, 0);                \
        a3 = __builtin_amdgcn_mfma_i32_32x32x32_i8(h1, z2, a3, 0, 0, 0);                \
        a3 = __builtin_amdgcn_mfma_i32_32x32x32_i8(h2, z1, a3, 0, 0, 0);                \
    }

#define KS_STAGED_LOOP                                                                  \
    _Pragma("unroll 2")                                                                 \
    for (int i = 0; i < 6; ++i) {                                                       \
        int ks = 10 + i;                                                                \
        int32x4 h1 = *(const int32x4*)(hp + (size_t)ks * 2048);                         \
        int32x4 h2 = *(const int32x4*)(h2s + i * 1024);                                 \
        int off = abase + ((ks * 32 + akb) ^ axor);                                     \
        int32x4 z1 = *(const int32x4*)(zr + off);                                       \
        int32x4 z2 = *(const int32x4*)(zr + 16384 + off);                               \
        a2 = __builtin_amdgcn_mfma_i32_32x32x32_i8(h1, z1, a2, 0, 0, 0);                \
        a3 = __builtin_amdgcn_mfma_i32_32x32x32_i8(h1, z2, a3, 0, 0, 0);                \
        a3 = __builtin_amdgcn_mfma_i32_32x32x32_i8(h2, z1, a3, 0, 0, 0);                \
    }

__launch_bounds__(1024)
__global__ void ctrnn_kernel(const float* __restrict__ x,
                             const int*   __restrict__ Tp,
                             const float* __restrict__ Iw,
                             const float* __restrict__ v,
                             const float* __restrict__ mb,
                             const uchar* __restrict__ Hpk,
                             const uchar* __restrict__ Opk,
                             float* __restrict__ out) {
    // 160 KB: 2 z-dbufs (64 KB) + h2 stage for ks 10..15 (96 KB)
    __shared__ uint4 zs4[10240];
    char* zsc = (char*)zs4;

    const int T   = Tp[0];
    const int tid = threadIdx.x;
    const int l   = tid & 63;
    const int w   = tid >> 6;                    // wave 0..15; owns n in [w*32, w*32+32)
    const int b0  = blockIdx.x * BT;

    // zero buf 0 (z_0 = 0 -> both levels 0)
#pragma unroll
    for (int i = 0; i < 2; ++i) zs4[tid + i * 1024] = make_uint4(0, 0, 0, 0);

    // stage h2 (residual plane) for ks 10..15 into LDS (reused all T steps)
#pragma unroll
    for (int i = 0; i < 6; ++i) {
        const uchar* src = Hpk + (size_t)((w * 16 + 10 + i) * 2 + 1) * 1024 + (size_t)l * 16;
        *(uint4*)(zsc + 65536 + (((w * 6 + i) * 64 + l) << 4)) = *(const uint4*)src;
    }

    // drive: drv[r] = x[m]*Iw[n]+v[n], lane owns m = l&31, n = w*32 + nset(r)
    const float xm = x[b0 + (l & 31)];
    f32x16 drv;
#pragma unroll
    for (int r = 0; r < 16; ++r) {
        int n = w * 32 + (r & 3) + 8 * (r >> 2) + 4 * (l >> 5);
        drv[r] = fmaf(xm, Iw[n], v[n]);
    }

    // output bias per lane (loaded by ALL waves: out_gemm rotates across waves)
    float mbv[4] = {0.f, 0.f, 0.f, 0.f};
    if ((l >> 4) < 3) {
#pragma unroll
        for (int r = 0; r < 4; ++r) mbv[r] = mb[(l >> 4) * 4 + r];
    }

    // per-wave packed-H base: ((w*16 + ks)*2 + L)*1024 + l*16
    const uchar* hp = Hpk + (size_t)(w * 16) * 2048 + (size_t)l * 16;

    // staged h2 base in LDS
    const char* h2s = zsc + 65536 + ((w * 6 * 64 + l) << 4);

    // z B-frag addressing: col j = m = l&31, k = ks*32 + (l>>5)*16
    const int am    = l & 31;
    const int abase = am * 512;
    const int axor  = (am & 15) << 4;
    const int akb   = (l >> 5) * 16;

    const int odd = w & 1;   // wave-stagger: odd waves run the two sections swapped

    __syncthreads();

    for (int t = 0; t < T; ++t) {
        const char* zr = zsc + (t & 1) * 32768;
        char*       zw = zsc + ((t & 1) ^ 1) * 32768;

        // ---- phase 3 (2 rotating waves): y_{t-1} from z_t (current read buffer)
        if (((w & 14) == ((t & 7) * 2)) && t > 0)
            out_gemm(zr, Opk, mbv, w & 1, l, out, b0, t - 1, T);

        // ---- phase 1: 3-term i8 MFMA (exact int32 accumulation)
        // Wave-staggered section order: even waves global-first, odd waves staged-first,
        // so ingest bursts and LDS/MFMA bursts from different waves interleave.
        int32x16 a2 = {0}, a3 = {0};
        if (odd) {
            KS_STAGED_LOOP
            KS_GLOBAL_LOOP
        } else {
            KS_GLOBAL_LOOP
            KS_STAGED_LOOP
        }

        // ---- phase 2: u -> z = tanh(u) -> 2-level i8, packed b32 writes (lane-local)
        {
            const int h5 = l >> 5;
#pragma unroll
            for (int rq = 0; rq < 4; ++rq) {
                uint d1 = 0, d2 = 0;
#pragma unroll
                for (int e = 0; e < 4; ++e) {
                    int r = rq * 4 + e;
                    float s = (float)a2[r] + 0.0078125f * (float)a3[r];
                    float u = fmaf(S_COMB, s, drv[r]);
                    float ex = __expf(2.0f * u);
                    float z  = 1.0f - __fdividef(2.0f, ex + 1.0f);
                    float h  = z * 127.0f;
                    float Q1 = rintf(h);
                    float r1 = (h - Q1) * 128.0f;
                    float Q2 = rintf(r1);
                    d1 |= ((uint)((int)Q1 & 255)) << (8 * e);
                    d2 |= ((uint)((int)Q2 & 255)) << (8 * e);
                }
                int nb  = w * 32 + 8 * rq + 4 * h5;          // n of byte e=0
                int off = abase + (nb ^ axor);               // dword-aligned (xor bits 4..7)
                *(uint*)(zw + off)         = d1;
                *(uint*)(zw + 16384 + off) = d2;
            }
        }
        __syncthreads();   // z_{t+1} complete; all reads of z_t done
    }

    // ---- epilogue: y_{T-1} from z_T (waves 0,1)
    if (w < 2)
        out_gemm(zsc + (T & 1) * 32768, Opk, mbv, w, l, out, b0, T - 1, T);
}

extern "C" void kernel_launch(void* const* d_in, const int* in_sizes, int n_in,
                              void* d_out, int out_size, void* d_ws, size_t ws_size,
                              hipStream_t stream) {
    const float* x  = (const float*)d_in[0];
    const int*   T  = (const int*)d_in[1];
    const float* Iw = (const float*)d_in[2];
    const float* Hw = (const float*)d_in[3];
    const float* Ow = (const float*)d_in[4];
    const float* v  = (const float*)d_in[5];
    const float* m  = (const float*)d_in[6];
    float* out = (float*)d_out;

    uchar* Hpk = (uchar*)d_ws;                   // 16*16*2*1024 = 524288 B
    uchar* Opk = Hpk + 524288;                   // 2*8*1024   =  16384 B

    pack_h<<<dim3(128), dim3(256), 0, stream>>>(Hw, Hpk);
    pack_o<<<dim3(4),   dim3(256), 0, stream>>>(Ow, Opk);
    ctrnn_kernel<<<dim3(256), dim3(1024), 0, stream>>>(x, T, Iw, v, m, Hpk, Opk, out);
}